// Round 9
// baseline (48.837 us; speedup 1.0000x reference)
//
#include <hip/hip_runtime.h>

// ws layout (float offsets)
#define WS_T    0      // 324 floats: trig-basis tensor T[81][4]
#define WS_HQ   512    // 7840: hwq[k][pos] as float4 (quantum head weights)
#define WS_WA   8352   // 1960: wavg[k][pos] (residual-avg head weights)
#define WS_H4   10312  // 1960: hz4[k][p4] as float4
#define WS_H8   12272  // 360:  hz8[k][p8] as float4
#define WS_C10  12632  // 10:   per-class constant (hb + res_b terms)

__device__ __forceinline__ float4 f4fma(const float4 a, const float s, const float4 c) {
  return {fmaf(a.x, s, c.x), fmaf(a.y, s, c.y), fmaf(a.z, s, c.z), fmaf(a.w, s, c.w)};
}
__device__ __forceinline__ float4 f4fma4(const float4 a, const float4 b, const float4 c) {
  return {fmaf(a.x, b.x, c.x), fmaf(a.y, b.y, c.y), fmaf(a.z, b.z, c.z), fmaf(a.w, b.w, c.w)};
}
__device__ __forceinline__ float hsum4(const float4 a) {
  return a.x + a.y + a.z + a.w;
}

// ---------------------------------------------------------------------------
// Prep kernel, grid = 11 blocks.
// Blocks 0..9: fold head weights (unchanged, validated).
// Block 10: quantum tensor T, single wave, no barriers. NEW: the three
// rotations of one qubit share the same amplitude pairing -> one LDS
// read/write round-trip per (layer,qubit) instead of three.
// ---------------------------------------------------------------------------
__global__ __launch_bounds__(256) void prep_kernel(
    const float* __restrict__ qp, const float* __restrict__ hw,
    const float* __restrict__ res_w, const float* __restrict__ res_b,
    const float* __restrict__ hb, float* __restrict__ ws) {
  __shared__ float row[2352];
  __shared__ float cred[4];
  __shared__ float Sr[16][16];
  __shared__ float Si[16][16];
  __shared__ float csc[36], css[36];
  __shared__ float Afs[256][4];
  const int t = threadIdx.x;

  if (blockIdx.x < 10) {
    const int k = blockIdx.x;
    for (int i = t; i < 2352; i += 256) row[i] = hw[k * 2352 + i];
    __syncthreads();
    float cpart = 0.f;
    if (t < 196) {
      const int b12 = t * 12;
      float4 h = {row[b12], row[b12 + 1], row[b12 + 2], row[b12 + 3]};
      ((float4*)(ws + WS_HQ))[k * 196 + t] = h;
      float wa = 0.f;
#pragma unroll
      for (int c = 0; c < 4; ++c) {
        const float s3 = row[b12 + c] + row[b12 + 4 + c] + row[b12 + 8 + c];
        wa += res_w[c] * s3;
        cpart += res_b[c] * s3;
      }
      ws[WS_WA + k * 196 + t] = wa;
    }
    if (t < 49) {
      const int i4 = t / 7, j4 = t % 7;
      float4 s = {0.f, 0.f, 0.f, 0.f};
#pragma unroll
      for (int di = 0; di < 2; ++di)
#pragma unroll
        for (int dj = 0; dj < 2; ++dj) {
          const int pos = (2 * i4 + di) * 14 + 2 * j4 + dj;
          s.x += row[pos * 12 + 4]; s.y += row[pos * 12 + 5];
          s.z += row[pos * 12 + 6]; s.w += row[pos * 12 + 7];
        }
      ((float4*)(ws + WS_H4))[k * 49 + t] = s;
    }
    if (t < 9) {
      const int i8 = t / 3, j8 = t % 3;
      const int pi0 = (i8 == 0) ? 0 : ((i8 == 1) ? 5 : 9);
      const int pi1 = (i8 == 0) ? 5 : ((i8 == 1) ? 9 : 14);
      const int pj0 = (j8 == 0) ? 0 : ((j8 == 1) ? 5 : 9);
      const int pj1 = (j8 == 0) ? 5 : ((j8 == 1) ? 9 : 14);
      float4 s = {0.f, 0.f, 0.f, 0.f};
      for (int pi = pi0; pi < pi1; ++pi)
        for (int pj = pj0; pj < pj1; ++pj) {
          const int pos = pi * 14 + pj;
          s.x += row[pos * 12 + 8]; s.y += row[pos * 12 + 9];
          s.z += row[pos * 12 + 10]; s.w += row[pos * 12 + 11];
        }
      ((float4*)(ws + WS_H8))[k * 9 + t] = s;
    }
#pragma unroll
    for (int off = 32; off > 0; off >>= 1) cpart += __shfl_xor(cpart, off);
    if ((t & 63) == 0) cred[t >> 6] = cpart;
    __syncthreads();
    if (t == 0) ws[WS_C10 + k] = hb[k] + cred[0] + cred[1] + cred[2] + cred[3];
    return;
  }

  // ---- block 10: quantum tensor T, single wave, no barriers ----
  if (t >= 64) return;

  if (t < 36) {
    float th = 0.5f * qp[t];
    csc[t] = cosf(th);
    css[t] = sinf(th);
  }
#pragma unroll
  for (int h = 0; h < 4; ++h) {
    const int idx = t + 64 * h;
    Sr[idx >> 4][idx & 15] = ((idx >> 4) == (idx & 15)) ? 1.f : 0.f;
    Si[idx >> 4][idx & 15] = 0.f;
  }

  for (int l = 0; l < 3; ++l) {
    for (int q = 0; q < 4; ++q) {
      const int m = 8 >> q;
      const float cx = csc[l * 12 + q * 3 + 0], sx = css[l * 12 + q * 3 + 0];
      const float cy = csc[l * 12 + q * 3 + 1], sy = css[l * 12 + q * 3 + 1];
      const float cz = csc[l * 12 + q * 3 + 2], sz = css[l * 12 + q * 3 + 2];
#pragma unroll
      for (int h = 0; h < 2; ++h) {
        const int idx = t + 64 * h;       // 0..127: 16 cols x 8 pairs
        const int col = idx >> 3, pp = idx & 7;
        const int k = ((pp & ~(m - 1)) << 1) | (pp & (m - 1));
        const int k1 = k | m;
        float a0r = Sr[col][k],  a0i = Si[col][k];
        float a1r = Sr[col][k1], a1i = Si[col][k1];
        // RX
        const float x0r = cx * a0r + sx * a1i, x0i = cx * a0i - sx * a1r;
        const float x1r = cx * a1r + sx * a0i, x1i = cx * a1i - sx * a0r;
        // RY
        const float y0r = cy * x0r - sy * x1r, y0i = cy * x0i - sy * x1i;
        const float y1r = sy * x0r + cy * x1r, y1i = sy * x0i + cy * x1i;
        // RZ
        a0r = cz * y0r + sz * y0i;  a0i = cz * y0i - sz * y0r;
        a1r = cz * y1r - sz * y1i;  a1i = cz * y1i + sz * y1r;
        Sr[col][k] = a0r;  Si[col][k] = a0i;
        Sr[col][k1] = a1r; Si[col][k1] = a1i;
      }
    }
    for (int e = 0; e < 4; ++e) {
      const int c2 = t >> 2, p2 = t & 3;
      const int mc = 8 >> e;
      const int mt = 8 >> ((e + 1) & 3);
      const int rest = 15 & ~(mc | mt);
      const int rl = rest & (-rest);
      const int rh = rest ^ rl;
      const int k = mc | ((p2 & 1) ? rl : 0) | ((p2 & 2) ? rh : 0);
      const int k1 = k | mt;
      float tr = Sr[c2][k]; Sr[c2][k] = Sr[c2][k1]; Sr[c2][k1] = tr;
      float ti = Si[c2][k]; Si[c2][k] = Si[c2][k1]; Si[c2][k1] = ti;
    }
  }

#pragma unroll
  for (int h = 0; h < 4; ++h) {
    const int o = t + 64 * h;
    const int i = o >> 4, j = o & 15;
    float a0 = 0.f, a1 = 0.f, a2 = 0.f, a3 = 0.f;
    for (int k = 0; k < 16; ++k) {
      float pr = Sr[i][k] * Sr[j][k] + Si[i][k] * Si[j][k];
      a0 += (k & 8) ? -pr : pr;
      a1 += (k & 4) ? -pr : pr;
      a2 += (k & 2) ? -pr : pr;
      a3 += (k & 1) ? -pr : pr;
    }
    Afs[o][0] = a0; Afs[o][1] = a1; Afs[o][2] = a2; Afs[o][3] = a3;
  }

#pragma unroll
  for (int h = 0; h < 6; ++h) {
    const int o = t + 64 * h;
    if (o < 324) {
      const int mi = o >> 2, q = o & 3;
      const int m0 = mi / 27, m1 = (mi / 9) % 3, m2 = (mi / 3) % 3, m3 = mi % 3;
      const int mm[4] = {m0, m1, m2, m3};
      float acc = 0.f;
      for (int c = 0; c < 16; ++c) {
        int ii = 0, jj = 0; float sg = 1.f;
        for (int qb = 0; qb < 4; ++qb) {
          const int cb = (c >> qb) & 1, bit = 8 >> qb, mq = mm[qb];
          if (mq == 2) { if (cb) ii |= bit; else jj |= bit; }
          else if (cb) { ii |= bit; jj |= bit; if (mq == 1) sg = -sg; }
        }
        acc += sg * Afs[ii * 16 + jj][q];
      }
      ws[WS_T + mi * 4 + q] = acc * 0.0625f;
    }
  }
}

// ---------------------------------------------------------------------------
// Main kernel: ONE IMAGE PER 128-THREAD BLOCK, two waves per image
// (8192 waves = up to 6 waves/SIMD at the 85-VGPR cap). Each wave stages
// its half and runs a lean 2-slot quantum body; feats split by wave after
// one barrier; pairwise logit combine via LDS.
// ---------------------------------------------------------------------------
__global__ __launch_bounds__(128, 6) void qmain_kernel(
    const float* __restrict__ x, const float4* __restrict__ T4,
    const float4* __restrict__ HQ4, const float* __restrict__ WA,
    const float4* __restrict__ H44, const float4* __restrict__ H84,
    const float* __restrict__ C10,
    const float* __restrict__ dw4_w, const float* __restrict__ dw4_b,
    const float* __restrict__ pw4_w, const float* __restrict__ pw4_b,
    const float* __restrict__ dw8_w, const float* __restrict__ dw8_b,
    const float* __restrict__ pw8_w, const float* __restrict__ pw8_b,
    float* __restrict__ out) {
  __shared__ __align__(16) float xw[792];
  __shared__ float accw[2][10];
  const int t = threadIdx.x;
  const int pw = t >> 6, lane = t & 63;
  const int img = blockIdx.x;
  const float4* xw4 = (const float4*)xw;

  {
    // each wave stages its own half (float4 idx [pw*98, pw*98+98))
    const float4* xg = (const float4*)(x + img * 784);
    const int i0 = pw * 98 + lane;
    ((float4*)xw)[i0] = xg[i0];
    if (lane < 34) {
      const int i1 = pw * 98 + 64 + lane;
      ((float4*)xw)[i1] = xg[i1];
    }
  }

  float acc[10];
#pragma unroll
  for (int k = 0; k < 10; ++k) acc[k] = 0.f;

  // ---- quantum: 2 slots per lane on own half (wave-private rows) ----
  if (lane < 49) {
    float cc[2][4], ss[2][4], av[2];
#pragma unroll
    for (int s = 0; s < 2; ++s) {
      const int p = 98 * pw + 49 * s + lane;
      const int base = 56 * (p / 14) + 2 * (p % 14);
      const float2 a01 = *(const float2*)(xw + base);
      const float2 a23 = *(const float2*)(xw + base + 28);
      __sincosf(a01.x, &ss[s][0], &cc[s][0]);
      __sincosf(a01.y, &ss[s][1], &cc[s][1]);
      __sincosf(a23.x, &ss[s][2], &cc[s][2]);
      __sincosf(a23.y, &ss[s][3], &cc[s][3]);
      av[s] = 0.25f * (a01.x + a01.y + a23.x + a23.y);
    }
    float4 e[2];
    e[0] = {0.f, 0.f, 0.f, 0.f};
    e[1] = {0.f, 0.f, 0.f, 0.f};
#pragma unroll 1
    for (int g = 0; g < 9; ++g) {
      const float4 t0 = T4[g * 9 + 0], t1 = T4[g * 9 + 1], t2 = T4[g * 9 + 2];
      const float4 t3 = T4[g * 9 + 3], t4 = T4[g * 9 + 4], t5 = T4[g * 9 + 5];
      const float4 t6 = T4[g * 9 + 6], t7 = T4[g * 9 + 7], t8 = T4[g * 9 + 8];
      const int m0 = g / 3, m1 = g % 3;
#pragma unroll
      for (int s = 0; s < 2; ++s) {
        const float c3 = cc[s][3], s3 = ss[s][3];
        const float4 u0 = f4fma(t2, s3, f4fma(t1, c3, t0));
        const float4 u1 = f4fma(t5, s3, f4fma(t4, c3, t3));
        const float4 u2 = f4fma(t8, s3, f4fma(t7, c3, t6));
        const float4 inner = f4fma(u2, ss[s][2], f4fma(u1, cc[s][2], u0));
        const float f0 = (m0 == 0) ? 1.f : ((m0 == 1) ? cc[s][0] : ss[s][0]);
        const float f1 = (m1 == 0) ? 1.f : ((m1 == 1) ? cc[s][1] : ss[s][1]);
        const float wf = (m0 == 0) ? f1 : ((m1 == 0) ? f0 : f0 * f1);
        e[s] = f4fma(inner, wf, e[s]);
      }
    }
    // head dot for the 2 slots
#pragma unroll
    for (int k = 0; k < 10; ++k) {
      float a = 0.f;
#pragma unroll
      for (int s = 0; s < 2; ++s) {
        const int p = 98 * pw + 49 * s + lane;
        const float4 h = HQ4[k * 196 + p];
        a += fmaf(h.x, e[s].x, fmaf(h.y, e[s].y,
             fmaf(h.z, e[s].z, fmaf(h.w, e[s].w, WA[k * 196 + p] * av[s]))));
      }
      acc[k] = a;
    }
  }
  __syncthreads();  // full image staged (feats span both halves)

  if (pw == 0) {
    if (lane < 49) {
      // ---- feat4: 4x4 stride-4 dw + 1x1 + relu + head dot ----
      const int u = lane;
      const int i = u / 7, j = u % 7;
      const float4* w44 = (const float4*)dw4_w;
      float4 q0 = {0.f, 0.f, 0.f, 0.f}, q1 = q0, q2 = q0, q3 = q0;
#pragma unroll
      for (int uu = 0; uu < 4; ++uu) {
        const float4 xa = xw4[(4 * i + uu) * 7 + j];
        q0 = f4fma4(w44[0 + uu], xa, q0);
        q1 = f4fma4(w44[4 + uu], xa, q1);
        q2 = f4fma4(w44[8 + uu], xa, q2);
        q3 = f4fma4(w44[12 + uu], xa, q3);
      }
      const float y0 = hsum4(q0) + dw4_b[0];
      const float y1 = hsum4(q1) + dw4_b[1];
      const float y2 = hsum4(q2) + dw4_b[2];
      const float y3 = hsum4(q3) + dw4_b[3];
      float z[4];
#pragma unroll
      for (int o = 0; o < 4; ++o) {
        float zz = pw4_b[o];
        zz = fmaf(pw4_w[o * 4 + 0], y0, zz);
        zz = fmaf(pw4_w[o * 4 + 1], y1, zz);
        zz = fmaf(pw4_w[o * 4 + 2], y2, zz);
        zz = fmaf(pw4_w[o * 4 + 3], y3, zz);
        z[o] = fmaxf(zz, 0.f);
      }
#pragma unroll
      for (int k = 0; k < 10; ++k) {
        const float4 h = H44[k * 49 + u];
        acc[k] += fmaf(h.x, z[0], fmaf(h.y, z[1], fmaf(h.z, z[2], h.w * z[3])));
      }
    }
  } else {
    if (lane < 9) {
      // ---- feat8: 8x8 stride-8 dw (4 ch) + 1x1 + relu + head dot ----
      const int pos = lane;
      const int i8 = pos / 3, j8 = pos % 3;
      const float4* w84 = (const float4*)dw8_w;
      float4 e0 = {0.f, 0.f, 0.f, 0.f}, e1 = e0, e2 = e0, e3 = e0;
#pragma unroll
      for (int uu = 0; uu < 8; ++uu) {
        const float4 xa = xw4[(8 * i8 + uu) * 7 + 2 * j8];
        const float4 xb = xw4[(8 * i8 + uu) * 7 + 2 * j8 + 1];
        e0 = f4fma4(w84[0 + uu * 2], xa, e0);
        e0 = f4fma4(w84[1 + uu * 2], xb, e0);
        e1 = f4fma4(w84[16 + uu * 2], xa, e1);
        e1 = f4fma4(w84[17 + uu * 2], xb, e1);
        e2 = f4fma4(w84[32 + uu * 2], xa, e2);
        e2 = f4fma4(w84[33 + uu * 2], xb, e2);
        e3 = f4fma4(w84[48 + uu * 2], xa, e3);
        e3 = f4fma4(w84[49 + uu * 2], xb, e3);
      }
      const float d0 = hsum4(e0) + dw8_b[0];
      const float d1 = hsum4(e1) + dw8_b[1];
      const float d2 = hsum4(e2) + dw8_b[2];
      const float d3 = hsum4(e3) + dw8_b[3];
      float z[4];
#pragma unroll
      for (int o = 0; o < 4; ++o) {
        float zz = pw8_b[o];
        zz = fmaf(pw8_w[o * 4 + 0], d0, zz);
        zz = fmaf(pw8_w[o * 4 + 1], d1, zz);
        zz = fmaf(pw8_w[o * 4 + 2], d2, zz);
        zz = fmaf(pw8_w[o * 4 + 3], d3, zz);
        z[o] = fmaxf(zz, 0.f);
      }
#pragma unroll
      for (int k = 0; k < 10; ++k) {
        const float4 h = H84[k * 9 + pos];
        acc[k] += fmaf(h.x, z[0], fmaf(h.y, z[1], fmaf(h.z, z[2], h.w * z[3])));
      }
    }
  }

  // ---- per-wave butterfly reduction ----
#pragma unroll
  for (int k = 0; k < 10; ++k) {
    float v = acc[k];
    v += __shfl_xor(v, 1);
    v += __shfl_xor(v, 2);
    v += __shfl_xor(v, 4);
    v += __shfl_xor(v, 8);
    v += __shfl_xor(v, 16);
    v += __shfl_xor(v, 32);
    acc[k] = v;
  }
  {
    float v = acc[0];
#pragma unroll
    for (int k = 1; k < 10; ++k)
      if (lane == k) v = acc[k];
    if (lane < 10) accw[pw][lane] = v;
  }
  __syncthreads();

  // ---- combine + log-softmax (wave 0) ----
  if (pw == 0) {
    float lg = -1e30f;
    if (lane < 10) lg = accw[0][lane] + accw[1][lane] + C10[lane];
    float mx = lg;
    mx = fmaxf(mx, __shfl_xor(mx, 1));
    mx = fmaxf(mx, __shfl_xor(mx, 2));
    mx = fmaxf(mx, __shfl_xor(mx, 4));
    mx = fmaxf(mx, __shfl_xor(mx, 8));
    float ex = (lane < 10) ? __expf(lg - mx) : 0.f;
    ex += __shfl_xor(ex, 1);
    ex += __shfl_xor(ex, 2);
    ex += __shfl_xor(ex, 4);
    ex += __shfl_xor(ex, 8);
    if (lane < 10) out[img * 10 + lane] = lg - mx - __logf(ex);
  }
}

extern "C" void kernel_launch(void* const* d_in, const int* in_sizes, int n_in,
                              void* d_out, int out_size, void* d_ws, size_t ws_size,
                              hipStream_t stream) {
  const float* x      = (const float*)d_in[0];
  const float* qp     = (const float*)d_in[1];
  const float* dw4_w  = (const float*)d_in[2];
  const float* dw4_b  = (const float*)d_in[3];
  const float* pw4_w  = (const float*)d_in[4];
  const float* pw4_b  = (const float*)d_in[5];
  const float* dw8_w  = (const float*)d_in[6];
  const float* dw8_b  = (const float*)d_in[7];
  const float* pw8_w  = (const float*)d_in[8];
  const float* pw8_b  = (const float*)d_in[9];
  const float* res_w  = (const float*)d_in[10];
  const float* res_b  = (const float*)d_in[11];
  const float* head_w = (const float*)d_in[12];
  const float* head_b = (const float*)d_in[13];
  float* out = (float*)d_out;
  float* ws = (float*)d_ws;
  const int B = in_sizes[0] / 784;

  hipLaunchKernelGGL(prep_kernel, dim3(11), dim3(256), 0, stream,
                     qp, head_w, res_w, res_b, head_b, ws);
  hipLaunchKernelGGL(qmain_kernel, dim3(B), dim3(128), 0, stream,
                     x, (const float4*)(ws + WS_T),
                     (const float4*)(ws + WS_HQ), ws + WS_WA,
                     (const float4*)(ws + WS_H4), (const float4*)(ws + WS_H8),
                     ws + WS_C10,
                     dw4_w, dw4_b, pw4_w, pw4_b, dw8_w, dw8_b, pw8_w, pw8_b,
                     out);
}

// Round 10
// 42.550 us; speedup vs baseline: 1.1478x; 1.1478x over previous
//
#include <hip/hip_runtime.h>

// ws layout (float offsets)
#define WS_T    0        // 324 floats: trig-basis tensor T[81][4]
#define WS_HQ   512      // 7840: hwq[k][pos] as float4
#define WS_WA   8352     // 1960: wavg[k][pos]
#define WS_H4   10312    // 1960: hz4[k][p4] as float4
#define WS_H8   12272    // 360:  hz8[k][p8] as float4
#define WS_C10  12632    // 10:   per-class constant
#define WS_E4   262144   // B*196*4 floats: quantum features (float4)
#define WS_AV   3473408  // B*196 floats: patch average

__device__ __forceinline__ float4 f4fma(const float4 a, const float s, const float4 c) {
  return {fmaf(a.x, s, c.x), fmaf(a.y, s, c.y), fmaf(a.z, s, c.z), fmaf(a.w, s, c.w)};
}
__device__ __forceinline__ float4 f4fma4(const float4 a, const float4 b, const float4 c) {
  return {fmaf(a.x, b.x, c.x), fmaf(a.y, b.y, c.y), fmaf(a.z, b.z, c.z), fmaf(a.w, b.w, c.w)};
}
__device__ __forceinline__ float hsum4(const float4 a) {
  return a.x + a.y + a.z + a.w;
}

// ---------------------------------------------------------------------------
// Prep kernel, grid = 11 blocks (validated round 9).
// ---------------------------------------------------------------------------
__global__ __launch_bounds__(256) void prep_kernel(
    const float* __restrict__ qp, const float* __restrict__ hw,
    const float* __restrict__ res_w, const float* __restrict__ res_b,
    const float* __restrict__ hb, float* __restrict__ ws) {
  __shared__ float row[2352];
  __shared__ float cred[4];
  __shared__ float Sr[16][16];
  __shared__ float Si[16][16];
  __shared__ float csc[36], css[36];
  __shared__ float Afs[256][4];
  const int t = threadIdx.x;

  if (blockIdx.x < 10) {
    const int k = blockIdx.x;
    for (int i = t; i < 2352; i += 256) row[i] = hw[k * 2352 + i];
    __syncthreads();
    float cpart = 0.f;
    if (t < 196) {
      const int b12 = t * 12;
      float4 h = {row[b12], row[b12 + 1], row[b12 + 2], row[b12 + 3]};
      ((float4*)(ws + WS_HQ))[k * 196 + t] = h;
      float wa = 0.f;
#pragma unroll
      for (int c = 0; c < 4; ++c) {
        const float s3 = row[b12 + c] + row[b12 + 4 + c] + row[b12 + 8 + c];
        wa += res_w[c] * s3;
        cpart += res_b[c] * s3;
      }
      ws[WS_WA + k * 196 + t] = wa;
    }
    if (t < 49) {
      const int i4 = t / 7, j4 = t % 7;
      float4 s = {0.f, 0.f, 0.f, 0.f};
#pragma unroll
      for (int di = 0; di < 2; ++di)
#pragma unroll
        for (int dj = 0; dj < 2; ++dj) {
          const int pos = (2 * i4 + di) * 14 + 2 * j4 + dj;
          s.x += row[pos * 12 + 4]; s.y += row[pos * 12 + 5];
          s.z += row[pos * 12 + 6]; s.w += row[pos * 12 + 7];
        }
      ((float4*)(ws + WS_H4))[k * 49 + t] = s;
    }
    if (t < 9) {
      const int i8 = t / 3, j8 = t % 3;
      const int pi0 = (i8 == 0) ? 0 : ((i8 == 1) ? 5 : 9);
      const int pi1 = (i8 == 0) ? 5 : ((i8 == 1) ? 9 : 14);
      const int pj0 = (j8 == 0) ? 0 : ((j8 == 1) ? 5 : 9);
      const int pj1 = (j8 == 0) ? 5 : ((j8 == 1) ? 9 : 14);
      float4 s = {0.f, 0.f, 0.f, 0.f};
      for (int pi = pi0; pi < pi1; ++pi)
        for (int pj = pj0; pj < pj1; ++pj) {
          const int pos = pi * 14 + pj;
          s.x += row[pos * 12 + 8]; s.y += row[pos * 12 + 9];
          s.z += row[pos * 12 + 10]; s.w += row[pos * 12 + 11];
        }
      ((float4*)(ws + WS_H8))[k * 9 + t] = s;
    }
#pragma unroll
    for (int off = 32; off > 0; off >>= 1) cpart += __shfl_xor(cpart, off);
    if ((t & 63) == 0) cred[t >> 6] = cpart;
    __syncthreads();
    if (t == 0) ws[WS_C10 + k] = hb[k] + cred[0] + cred[1] + cred[2] + cred[3];
    return;
  }

  // ---- block 10: quantum tensor T, single wave, no barriers ----
  if (t >= 64) return;

  if (t < 36) {
    float th = 0.5f * qp[t];
    csc[t] = cosf(th);
    css[t] = sinf(th);
  }
#pragma unroll
  for (int h = 0; h < 4; ++h) {
    const int idx = t + 64 * h;
    Sr[idx >> 4][idx & 15] = ((idx >> 4) == (idx & 15)) ? 1.f : 0.f;
    Si[idx >> 4][idx & 15] = 0.f;
  }

  for (int l = 0; l < 3; ++l) {
    for (int q = 0; q < 4; ++q) {
      const int m = 8 >> q;
      const float cx = csc[l * 12 + q * 3 + 0], sx = css[l * 12 + q * 3 + 0];
      const float cy = csc[l * 12 + q * 3 + 1], sy = css[l * 12 + q * 3 + 1];
      const float cz = csc[l * 12 + q * 3 + 2], sz = css[l * 12 + q * 3 + 2];
#pragma unroll
      for (int h = 0; h < 2; ++h) {
        const int idx = t + 64 * h;
        const int col = idx >> 3, pp = idx & 7;
        const int k = ((pp & ~(m - 1)) << 1) | (pp & (m - 1));
        const int k1 = k | m;
        float a0r = Sr[col][k],  a0i = Si[col][k];
        float a1r = Sr[col][k1], a1i = Si[col][k1];
        const float x0r = cx * a0r + sx * a1i, x0i = cx * a0i - sx * a1r;
        const float x1r = cx * a1r + sx * a0i, x1i = cx * a1i - sx * a0r;
        const float y0r = cy * x0r - sy * x1r, y0i = cy * x0i - sy * x1i;
        const float y1r = sy * x0r + cy * x1r, y1i = sy * x0i + cy * x1i;
        a0r = cz * y0r + sz * y0i;  a0i = cz * y0i - sz * y0r;
        a1r = cz * y1r - sz * y1i;  a1i = cz * y1i + sz * y1r;
        Sr[col][k] = a0r;  Si[col][k] = a0i;
        Sr[col][k1] = a1r; Si[col][k1] = a1i;
      }
    }
    for (int e = 0; e < 4; ++e) {
      const int c2 = t >> 2, p2 = t & 3;
      const int mc = 8 >> e;
      const int mt = 8 >> ((e + 1) & 3);
      const int rest = 15 & ~(mc | mt);
      const int rl = rest & (-rest);
      const int rh = rest ^ rl;
      const int k = mc | ((p2 & 1) ? rl : 0) | ((p2 & 2) ? rh : 0);
      const int k1 = k | mt;
      float tr = Sr[c2][k]; Sr[c2][k] = Sr[c2][k1]; Sr[c2][k1] = tr;
      float ti = Si[c2][k]; Si[c2][k] = Si[c2][k1]; Si[c2][k1] = ti;
    }
  }

#pragma unroll
  for (int h = 0; h < 4; ++h) {
    const int o = t + 64 * h;
    const int i = o >> 4, j = o & 15;
    float a0 = 0.f, a1 = 0.f, a2 = 0.f, a3 = 0.f;
    for (int k = 0; k < 16; ++k) {
      float pr = Sr[i][k] * Sr[j][k] + Si[i][k] * Si[j][k];
      a0 += (k & 8) ? -pr : pr;
      a1 += (k & 4) ? -pr : pr;
      a2 += (k & 2) ? -pr : pr;
      a3 += (k & 1) ? -pr : pr;
    }
    Afs[o][0] = a0; Afs[o][1] = a1; Afs[o][2] = a2; Afs[o][3] = a3;
  }

#pragma unroll
  for (int h = 0; h < 6; ++h) {
    const int o = t + 64 * h;
    if (o < 324) {
      const int mi = o >> 2, q = o & 3;
      const int m0 = mi / 27, m1 = (mi / 9) % 3, m2 = (mi / 3) % 3, m3 = mi % 3;
      const int mm[4] = {m0, m1, m2, m3};
      float acc = 0.f;
      for (int c = 0; c < 16; ++c) {
        int ii = 0, jj = 0; float sg = 1.f;
        for (int qb = 0; qb < 4; ++qb) {
          const int cb = (c >> qb) & 1, bit = 8 >> qb, mq = mm[qb];
          if (mq == 2) { if (cb) ii |= bit; else jj |= bit; }
          else if (cb) { ii |= bit; jj |= bit; if (mq == 1) sg = -sg; }
        }
        acc += sg * Afs[ii * 16 + jj][q];
      }
      ws[WS_T + mi * 4 + q] = acc * 0.0625f;
    }
  }
}

// ---------------------------------------------------------------------------
// Kernel A: ONE THREAD PER PATCH (B*196 threads; ~12 waves/SIMD TLP).
// No LDS, no barriers. T4 accesses are compile-time-indexed (scalar loads).
// ---------------------------------------------------------------------------
__global__ __launch_bounds__(256) void qfeat_kernel(
    const float* __restrict__ x, const float4* __restrict__ T4,
    float4* __restrict__ e4out, float* __restrict__ avout, const int NP) {
  const int gp = blockIdx.x * 256 + threadIdx.x;
  if (gp >= NP) return;
  const int img = gp / 196, p = gp - img * 196;
  const int pi = p / 14, pj = p - pi * 14;
  const float* xb = x + img * 784 + 56 * pi + 2 * pj;
  const float2 a01 = *(const float2*)(xb);
  const float2 a23 = *(const float2*)(xb + 28);
  float c0, s0, c1, s1, c2, s2, c3, s3;
  __sincosf(a01.x, &s0, &c0);
  __sincosf(a01.y, &s1, &c1);
  __sincosf(a23.x, &s2, &c2);
  __sincosf(a23.y, &s3, &c3);
  const float w01[9] = {1.f, c1, s1, c0, c0 * c1, c0 * s1, s0, s0 * c1, s0 * s1};
  float4 e = {0.f, 0.f, 0.f, 0.f};
#pragma unroll
  for (int g = 0; g < 9; ++g) {
    const float4 t0 = T4[g * 9 + 0], t1 = T4[g * 9 + 1], t2 = T4[g * 9 + 2];
    const float4 t3 = T4[g * 9 + 3], t4 = T4[g * 9 + 4], t5 = T4[g * 9 + 5];
    const float4 t6 = T4[g * 9 + 6], t7 = T4[g * 9 + 7], t8 = T4[g * 9 + 8];
    const float4 u0 = f4fma(t2, s3, f4fma(t1, c3, t0));
    const float4 u1 = f4fma(t5, s3, f4fma(t4, c3, t3));
    const float4 u2 = f4fma(t8, s3, f4fma(t7, c3, t6));
    const float4 inner = f4fma(u2, s2, f4fma(u1, c2, u0));
    e = f4fma(inner, w01[g], e);
  }
  e4out[gp] = e;
  avout[gp] = 0.25f * (a01.x + a01.y + a23.x + a23.y);
}

// ---------------------------------------------------------------------------
// Kernel B: ONE WAVE PER IMAGE (R8 structure), quantum replaced by loads.
// Zero block barriers (wave-private LDS slab).
// ---------------------------------------------------------------------------
__global__ __launch_bounds__(256, 4) void qmain_kernel(
    const float* __restrict__ x, const float4* __restrict__ E4,
    const float* __restrict__ AV,
    const float4* __restrict__ HQ4, const float* __restrict__ WA,
    const float4* __restrict__ H44, const float4* __restrict__ H84,
    const float* __restrict__ C10,
    const float* __restrict__ dw4_w, const float* __restrict__ dw4_b,
    const float* __restrict__ pw4_w, const float* __restrict__ pw4_b,
    const float* __restrict__ dw8_w, const float* __restrict__ dw8_b,
    const float* __restrict__ pw8_w, const float* __restrict__ pw8_b,
    float* __restrict__ out, const int B) {
  __shared__ __align__(16) float xs[4 * 792];
  const int t = threadIdx.x;
  const int w = t >> 6, lane = t & 63;
  const int img = blockIdx.x * 4 + w;
  float* xw = xs + w * 792;
  const float4* xw4 = (const float4*)xw;
  const bool ok = (img < B);

  if (ok) {
    const float4* xg = (const float4*)(x + img * 784);
#pragma unroll
    for (int it = 0; it < 4; ++it) {
      const int idx = it * 64 + lane;
      if (idx < 196) ((float4*)xw)[idx] = xg[idx];
    }
  }
  // no barrier: slab private to this wave; DS ops are wave-ordered.

  float acc[10];
#pragma unroll
  for (int k = 0; k < 10; ++k) acc[k] = 0.f;

  if (ok && lane < 49) {
    // ---- quantum head dot from precomputed features ----
    float4 e[4];
    float av[4];
#pragma unroll
    for (int s = 0; s < 4; ++s) {
      const int gp = img * 196 + 49 * s + lane;
      e[s] = E4[gp];
      av[s] = AV[gp];
    }
#pragma unroll
    for (int k = 0; k < 10; ++k) {
      float a = 0.f;
#pragma unroll
      for (int s = 0; s < 4; ++s) {
        const int p = 49 * s + lane;
        const float4 h = HQ4[k * 196 + p];
        a += fmaf(h.x, e[s].x, fmaf(h.y, e[s].y,
             fmaf(h.z, e[s].z, fmaf(h.w, e[s].w, WA[k * 196 + p] * av[s]))));
      }
      acc[k] = a;
    }
    // ---- feat4 ----
    {
      const int u = lane;
      const int i = u / 7, j = u % 7;
      const float4* w44 = (const float4*)dw4_w;
      float4 q0 = {0.f, 0.f, 0.f, 0.f}, q1 = q0, q2 = q0, q3 = q0;
#pragma unroll
      for (int uu = 0; uu < 4; ++uu) {
        const float4 xa = xw4[(4 * i + uu) * 7 + j];
        q0 = f4fma4(w44[0 + uu], xa, q0);
        q1 = f4fma4(w44[4 + uu], xa, q1);
        q2 = f4fma4(w44[8 + uu], xa, q2);
        q3 = f4fma4(w44[12 + uu], xa, q3);
      }
      const float y0 = hsum4(q0) + dw4_b[0];
      const float y1 = hsum4(q1) + dw4_b[1];
      const float y2 = hsum4(q2) + dw4_b[2];
      const float y3 = hsum4(q3) + dw4_b[3];
      float z[4];
#pragma unroll
      for (int o = 0; o < 4; ++o) {
        float zz = pw4_b[o];
        zz = fmaf(pw4_w[o * 4 + 0], y0, zz);
        zz = fmaf(pw4_w[o * 4 + 1], y1, zz);
        zz = fmaf(pw4_w[o * 4 + 2], y2, zz);
        zz = fmaf(pw4_w[o * 4 + 3], y3, zz);
        z[o] = fmaxf(zz, 0.f);
      }
#pragma unroll
      for (int k = 0; k < 10; ++k) {
        const float4 h = H44[k * 49 + u];
        acc[k] += fmaf(h.x, z[0], fmaf(h.y, z[1], fmaf(h.z, z[2], h.w * z[3])));
      }
    }
  } else if (ok && lane >= 49 && lane < 58) {
    // ---- feat8 ----
    const int pos = lane - 49;
    const int i8 = pos / 3, j8 = pos % 3;
    const float4* w84 = (const float4*)dw8_w;
    float4 e0 = {0.f, 0.f, 0.f, 0.f}, e1 = e0, e2 = e0, e3 = e0;
#pragma unroll
    for (int uu = 0; uu < 8; ++uu) {
      const float4 xa = xw4[(8 * i8 + uu) * 7 + 2 * j8];
      const float4 xb = xw4[(8 * i8 + uu) * 7 + 2 * j8 + 1];
      e0 = f4fma4(w84[0 + uu * 2], xa, e0);
      e0 = f4fma4(w84[1 + uu * 2], xb, e0);
      e1 = f4fma4(w84[16 + uu * 2], xa, e1);
      e1 = f4fma4(w84[17 + uu * 2], xb, e1);
      e2 = f4fma4(w84[32 + uu * 2], xa, e2);
      e2 = f4fma4(w84[33 + uu * 2], xb, e2);
      e3 = f4fma4(w84[48 + uu * 2], xa, e3);
      e3 = f4fma4(w84[49 + uu * 2], xb, e3);
    }
    const float d0 = hsum4(e0) + dw8_b[0];
    const float d1 = hsum4(e1) + dw8_b[1];
    const float d2 = hsum4(e2) + dw8_b[2];
    const float d3 = hsum4(e3) + dw8_b[3];
    float z[4];
#pragma unroll
    for (int o = 0; o < 4; ++o) {
      float zz = pw8_b[o];
      zz = fmaf(pw8_w[o * 4 + 0], d0, zz);
      zz = fmaf(pw8_w[o * 4 + 1], d1, zz);
      zz = fmaf(pw8_w[o * 4 + 2], d2, zz);
      zz = fmaf(pw8_w[o * 4 + 3], d3, zz);
      z[o] = fmaxf(zz, 0.f);
    }
#pragma unroll
    for (int k = 0; k < 10; ++k) {
      const float4 h = H84[k * 9 + pos];
      acc[k] += fmaf(h.x, z[0], fmaf(h.y, z[1], fmaf(h.z, z[2], h.w * z[3])));
    }
  }

  if (!ok) return;

  // ---- 64-lane butterfly reduction ----
#pragma unroll
  for (int k = 0; k < 10; ++k) {
    float v = acc[k];
    v += __shfl_xor(v, 1);
    v += __shfl_xor(v, 2);
    v += __shfl_xor(v, 4);
    v += __shfl_xor(v, 8);
    v += __shfl_xor(v, 16);
    v += __shfl_xor(v, 32);
    acc[k] = v;
  }

  // ---- log-softmax in-registers ----
  float lg[10], m = -1e30f;
#pragma unroll
  for (int k = 0; k < 10; ++k) {
    lg[k] = acc[k] + C10[k];
    m = fmaxf(m, lg[k]);
  }
  float se = 0.f;
#pragma unroll
  for (int k = 0; k < 10; ++k) se += __expf(lg[k] - m);
  const float ls = m + __logf(se);
  if (lane < 10) {
    float v = lg[0];
#pragma unroll
    for (int k = 1; k < 10; ++k)
      if (lane == k) v = lg[k];
    out[img * 10 + lane] = v - ls;
  }
}

extern "C" void kernel_launch(void* const* d_in, const int* in_sizes, int n_in,
                              void* d_out, int out_size, void* d_ws, size_t ws_size,
                              hipStream_t stream) {
  const float* x      = (const float*)d_in[0];
  const float* qp     = (const float*)d_in[1];
  const float* dw4_w  = (const float*)d_in[2];
  const float* dw4_b  = (const float*)d_in[3];
  const float* pw4_w  = (const float*)d_in[4];
  const float* pw4_b  = (const float*)d_in[5];
  const float* dw8_w  = (const float*)d_in[6];
  const float* dw8_b  = (const float*)d_in[7];
  const float* pw8_w  = (const float*)d_in[8];
  const float* pw8_b  = (const float*)d_in[9];
  const float* res_w  = (const float*)d_in[10];
  const float* res_b  = (const float*)d_in[11];
  const float* head_w = (const float*)d_in[12];
  const float* head_b = (const float*)d_in[13];
  float* out = (float*)d_out;
  float* ws = (float*)d_ws;
  const int B = in_sizes[0] / 784;
  const int NP = B * 196;

  hipLaunchKernelGGL(prep_kernel, dim3(11), dim3(256), 0, stream,
                     qp, head_w, res_w, res_b, head_b, ws);
  hipLaunchKernelGGL(qfeat_kernel, dim3((NP + 255) / 256), dim3(256), 0, stream,
                     x, (const float4*)(ws + WS_T),
                     (float4*)(ws + WS_E4), ws + WS_AV, NP);
  hipLaunchKernelGGL(qmain_kernel, dim3((B + 3) / 4), dim3(256), 0, stream,
                     x, (const float4*)(ws + WS_E4), ws + WS_AV,
                     (const float4*)(ws + WS_HQ), ws + WS_WA,
                     (const float4*)(ws + WS_H4), (const float4*)(ws + WS_H8),
                     ws + WS_C10,
                     dw4_w, dw4_b, pw4_w, pw4_b, dw8_w, dw8_b, pw8_w, pw8_b,
                     out, B);
}

// Round 11
// 32.885 us; speedup vs baseline: 1.4851x; 1.2939x over previous
//
#include <hip/hip_runtime.h>

// ws layout (float offsets)
#define WS_T    0      // 324 floats: trig-basis tensor T[81][4]
#define WS_HQ   512    // 7840: hwq[k][pos] as float4
#define WS_WA   8352   // 1960: wavg[k][pos]
#define WS_H4   10312  // 1960: hz4[k][p4] as float4
#define WS_H8   12272  // 360:  hz8[k][p8] as float4
#define WS_C10  12632  // 10:   per-class constant

__device__ __forceinline__ float4 f4fma(const float4 a, const float s, const float4 c) {
  return {fmaf(a.x, s, c.x), fmaf(a.y, s, c.y), fmaf(a.z, s, c.z), fmaf(a.w, s, c.w)};
}
__device__ __forceinline__ float4 f4fma4(const float4 a, const float4 b, const float4 c) {
  return {fmaf(a.x, b.x, c.x), fmaf(a.y, b.y, c.y), fmaf(a.z, b.z, c.z), fmaf(a.w, b.w, c.w)};
}
__device__ __forceinline__ float hsum4(const float4 a) {
  return a.x + a.y + a.z + a.w;
}

// ---------------------------------------------------------------------------
// Prep kernel, grid = 11 blocks (validated rounds 9-10).
// ---------------------------------------------------------------------------
__global__ __launch_bounds__(256) void prep_kernel(
    const float* __restrict__ qp, const float* __restrict__ hw,
    const float* __restrict__ res_w, const float* __restrict__ res_b,
    const float* __restrict__ hb, float* __restrict__ ws) {
  __shared__ float row[2352];
  __shared__ float cred[4];
  __shared__ float Sr[16][16];
  __shared__ float Si[16][16];
  __shared__ float csc[36], css[36];
  __shared__ float Afs[256][4];
  const int t = threadIdx.x;

  if (blockIdx.x < 10) {
    const int k = blockIdx.x;
    for (int i = t; i < 2352; i += 256) row[i] = hw[k * 2352 + i];
    __syncthreads();
    float cpart = 0.f;
    if (t < 196) {
      const int b12 = t * 12;
      float4 h = {row[b12], row[b12 + 1], row[b12 + 2], row[b12 + 3]};
      ((float4*)(ws + WS_HQ))[k * 196 + t] = h;
      float wa = 0.f;
#pragma unroll
      for (int c = 0; c < 4; ++c) {
        const float s3 = row[b12 + c] + row[b12 + 4 + c] + row[b12 + 8 + c];
        wa += res_w[c] * s3;
        cpart += res_b[c] * s3;
      }
      ws[WS_WA + k * 196 + t] = wa;
    }
    if (t < 49) {
      const int i4 = t / 7, j4 = t % 7;
      float4 s = {0.f, 0.f, 0.f, 0.f};
#pragma unroll
      for (int di = 0; di < 2; ++di)
#pragma unroll
        for (int dj = 0; dj < 2; ++dj) {
          const int pos = (2 * i4 + di) * 14 + 2 * j4 + dj;
          s.x += row[pos * 12 + 4]; s.y += row[pos * 12 + 5];
          s.z += row[pos * 12 + 6]; s.w += row[pos * 12 + 7];
        }
      ((float4*)(ws + WS_H4))[k * 49 + t] = s;
    }
    if (t < 9) {
      const int i8 = t / 3, j8 = t % 3;
      const int pi0 = (i8 == 0) ? 0 : ((i8 == 1) ? 5 : 9);
      const int pi1 = (i8 == 0) ? 5 : ((i8 == 1) ? 9 : 14);
      const int pj0 = (j8 == 0) ? 0 : ((j8 == 1) ? 5 : 9);
      const int pj1 = (j8 == 0) ? 5 : ((j8 == 1) ? 9 : 14);
      float4 s = {0.f, 0.f, 0.f, 0.f};
      for (int pi = pi0; pi < pi1; ++pi)
        for (int pj = pj0; pj < pj1; ++pj) {
          const int pos = pi * 14 + pj;
          s.x += row[pos * 12 + 8]; s.y += row[pos * 12 + 9];
          s.z += row[pos * 12 + 10]; s.w += row[pos * 12 + 11];
        }
      ((float4*)(ws + WS_H8))[k * 9 + t] = s;
    }
#pragma unroll
    for (int off = 32; off > 0; off >>= 1) cpart += __shfl_xor(cpart, off);
    if ((t & 63) == 0) cred[t >> 6] = cpart;
    __syncthreads();
    if (t == 0) ws[WS_C10 + k] = hb[k] + cred[0] + cred[1] + cred[2] + cred[3];
    return;
  }

  // ---- block 10: quantum tensor T, single wave, no barriers ----
  if (t >= 64) return;

  if (t < 36) {
    float th = 0.5f * qp[t];
    csc[t] = cosf(th);
    css[t] = sinf(th);
  }
#pragma unroll
  for (int h = 0; h < 4; ++h) {
    const int idx = t + 64 * h;
    Sr[idx >> 4][idx & 15] = ((idx >> 4) == (idx & 15)) ? 1.f : 0.f;
    Si[idx >> 4][idx & 15] = 0.f;
  }

  for (int l = 0; l < 3; ++l) {
    for (int q = 0; q < 4; ++q) {
      const int m = 8 >> q;
      const float cx = csc[l * 12 + q * 3 + 0], sx = css[l * 12 + q * 3 + 0];
      const float cy = csc[l * 12 + q * 3 + 1], sy = css[l * 12 + q * 3 + 1];
      const float cz = csc[l * 12 + q * 3 + 2], sz = css[l * 12 + q * 3 + 2];
#pragma unroll
      for (int h = 0; h < 2; ++h) {
        const int idx = t + 64 * h;
        const int col = idx >> 3, pp = idx & 7;
        const int k = ((pp & ~(m - 1)) << 1) | (pp & (m - 1));
        const int k1 = k | m;
        float a0r = Sr[col][k],  a0i = Si[col][k];
        float a1r = Sr[col][k1], a1i = Si[col][k1];
        const float x0r = cx * a0r + sx * a1i, x0i = cx * a0i - sx * a1r;
        const float x1r = cx * a1r + sx * a0i, x1i = cx * a1i - sx * a0r;
        const float y0r = cy * x0r - sy * x1r, y0i = cy * x0i - sy * x1i;
        const float y1r = sy * x0r + cy * x1r, y1i = sy * x0i + cy * x1i;
        a0r = cz * y0r + sz * y0i;  a0i = cz * y0i - sz * y0r;
        a1r = cz * y1r - sz * y1i;  a1i = cz * y1i + sz * y1r;
        Sr[col][k] = a0r;  Si[col][k] = a0i;
        Sr[col][k1] = a1r; Si[col][k1] = a1i;
      }
    }
    for (int e = 0; e < 4; ++e) {
      const int c2 = t >> 2, p2 = t & 3;
      const int mc = 8 >> e;
      const int mt = 8 >> ((e + 1) & 3);
      const int rest = 15 & ~(mc | mt);
      const int rl = rest & (-rest);
      const int rh = rest ^ rl;
      const int k = mc | ((p2 & 1) ? rl : 0) | ((p2 & 2) ? rh : 0);
      const int k1 = k | mt;
      float tr = Sr[c2][k]; Sr[c2][k] = Sr[c2][k1]; Sr[c2][k1] = tr;
      float ti = Si[c2][k]; Si[c2][k] = Si[c2][k1]; Si[c2][k1] = ti;
    }
  }

#pragma unroll
  for (int h = 0; h < 4; ++h) {
    const int o = t + 64 * h;
    const int i = o >> 4, j = o & 15;
    float a0 = 0.f, a1 = 0.f, a2 = 0.f, a3 = 0.f;
    for (int k = 0; k < 16; ++k) {
      float pr = Sr[i][k] * Sr[j][k] + Si[i][k] * Si[j][k];
      a0 += (k & 8) ? -pr : pr;
      a1 += (k & 4) ? -pr : pr;
      a2 += (k & 2) ? -pr : pr;
      a3 += (k & 1) ? -pr : pr;
    }
    Afs[o][0] = a0; Afs[o][1] = a1; Afs[o][2] = a2; Afs[o][3] = a3;
  }

#pragma unroll
  for (int h = 0; h < 6; ++h) {
    const int o = t + 64 * h;
    if (o < 324) {
      const int mi = o >> 2, q = o & 3;
      const int m0 = mi / 27, m1 = (mi / 9) % 3, m2 = (mi / 3) % 3, m3 = mi % 3;
      const int mm[4] = {m0, m1, m2, m3};
      float acc = 0.f;
      for (int c = 0; c < 16; ++c) {
        int ii = 0, jj = 0; float sg = 1.f;
        for (int qb = 0; qb < 4; ++qb) {
          const int cb = (c >> qb) & 1, bit = 8 >> qb, mq = mm[qb];
          if (mq == 2) { if (cb) ii |= bit; else jj |= bit; }
          else if (cb) { ii |= bit; jj |= bit; if (mq == 1) sg = -sg; }
        }
        acc += sg * Afs[ii * 16 + jj][q];
      }
      ws[WS_T + mi * 4 + q] = acc * 0.0625f;
    }
  }
}

// ---------------------------------------------------------------------------
// Main kernel: TWO WAVES PER IMAGE (8192 waves), 256-thr blocks = 2 images.
// Lean 2-slot body: per slot, compute e then immediately dot into acc[10]
// (no batched state). Cap 102 VGPR -> >=5 waves/SIMD without spilling.
// ---------------------------------------------------------------------------
__global__ __launch_bounds__(256, 5) void qmain_kernel(
    const float* __restrict__ x, const float4* __restrict__ T4,
    const float4* __restrict__ HQ4, const float* __restrict__ WA,
    const float4* __restrict__ H44, const float4* __restrict__ H84,
    const float* __restrict__ C10,
    const float* __restrict__ dw4_w, const float* __restrict__ dw4_b,
    const float* __restrict__ pw4_w, const float* __restrict__ pw4_b,
    const float* __restrict__ dw8_w, const float* __restrict__ dw8_b,
    const float* __restrict__ pw8_w, const float* __restrict__ pw8_b,
    float* __restrict__ out, const int B) {
  __shared__ __align__(16) float xs[2 * 792];
  __shared__ float accw[4][10];
  const int t = threadIdx.x;
  const int w = t >> 6, lane = t & 63;
  const int il = w >> 1, pw = w & 1;
  const int img = blockIdx.x * 2 + il;
  float* xw = xs + il * 792;
  const float4* xw4 = (const float4*)xw;
  const bool ok = (img < B);

  if (ok) {
    // each wave stages its own half (float4 idx [pw*98, pw*98+98))
    const float4* xg = (const float4*)(x + img * 784);
    const int i0 = pw * 98 + lane;
    ((float4*)xw)[i0] = xg[i0];
    if (lane < 34) {
      const int i1 = pw * 98 + 64 + lane;
      ((float4*)xw)[i1] = xg[i1];
    }
  }

  float acc[10];
#pragma unroll
  for (int k = 0; k < 10; ++k) acc[k] = 0.f;

  // ---- quantum: 2 slots, e computed and dotted per slot (lean live set) ----
  if (ok && lane < 49) {
#pragma unroll 1
    for (int s = 0; s < 2; ++s) {
      const int p = 98 * pw + 49 * s + lane;
      const int base = 56 * (p / 14) + 2 * (p % 14);
      const float2 a01 = *(const float2*)(xw + base);
      const float2 a23 = *(const float2*)(xw + base + 28);
      float c0, s0, c1, s1, c2, s2, c3, s3;
      __sincosf(a01.x, &s0, &c0);
      __sincosf(a01.y, &s1, &c1);
      __sincosf(a23.x, &s2, &c2);
      __sincosf(a23.y, &s3, &c3);
      const float w01[9] = {1.f, c1, s1, c0, c0 * c1, c0 * s1, s0, s0 * c1, s0 * s1};
      float4 e = {0.f, 0.f, 0.f, 0.f};
#pragma unroll 1
      for (int g = 0; g < 9; ++g) {
        const float4 t0 = T4[g * 9 + 0], t1 = T4[g * 9 + 1], t2 = T4[g * 9 + 2];
        const float4 t3 = T4[g * 9 + 3], t4 = T4[g * 9 + 4], t5 = T4[g * 9 + 5];
        const float4 t6 = T4[g * 9 + 6], t7 = T4[g * 9 + 7], t8 = T4[g * 9 + 8];
        const float4 u0 = f4fma(t2, s3, f4fma(t1, c3, t0));
        const float4 u1 = f4fma(t5, s3, f4fma(t4, c3, t3));
        const float4 u2 = f4fma(t8, s3, f4fma(t7, c3, t6));
        const float4 inner = f4fma(u2, s2, f4fma(u1, c2, u0));
        e = f4fma(inner, w01[g], e);
      }
      const float av = 0.25f * (a01.x + a01.y + a23.x + a23.y);
#pragma unroll
      for (int k = 0; k < 10; ++k) {
        const float4 h = HQ4[k * 196 + p];
        acc[k] += fmaf(h.x, e.x, fmaf(h.y, e.y,
                  fmaf(h.z, e.z, fmaf(h.w, e.w, WA[k * 196 + p] * av))));
      }
    }
  }
  __syncthreads();  // full image staged (feats span both halves)

  if (ok) {
    if (pw == 0) {
      if (lane < 49) {
        // ---- feat4 ----
        const int u = lane;
        const int i = u / 7, j = u % 7;
        const float4* w44 = (const float4*)dw4_w;
        float4 q0 = {0.f, 0.f, 0.f, 0.f}, q1 = q0, q2 = q0, q3 = q0;
#pragma unroll
        for (int uu = 0; uu < 4; ++uu) {
          const float4 xa = xw4[(4 * i + uu) * 7 + j];
          q0 = f4fma4(w44[0 + uu], xa, q0);
          q1 = f4fma4(w44[4 + uu], xa, q1);
          q2 = f4fma4(w44[8 + uu], xa, q2);
          q3 = f4fma4(w44[12 + uu], xa, q3);
        }
        const float y0 = hsum4(q0) + dw4_b[0];
        const float y1 = hsum4(q1) + dw4_b[1];
        const float y2 = hsum4(q2) + dw4_b[2];
        const float y3 = hsum4(q3) + dw4_b[3];
        float z[4];
#pragma unroll
        for (int o = 0; o < 4; ++o) {
          float zz = pw4_b[o];
          zz = fmaf(pw4_w[o * 4 + 0], y0, zz);
          zz = fmaf(pw4_w[o * 4 + 1], y1, zz);
          zz = fmaf(pw4_w[o * 4 + 2], y2, zz);
          zz = fmaf(pw4_w[o * 4 + 3], y3, zz);
          z[o] = fmaxf(zz, 0.f);
        }
#pragma unroll
        for (int k = 0; k < 10; ++k) {
          const float4 h = H44[k * 49 + u];
          acc[k] += fmaf(h.x, z[0], fmaf(h.y, z[1], fmaf(h.z, z[2], h.w * z[3])));
        }
      }
    } else {
      if (lane < 9) {
        // ---- feat8 ----
        const int pos = lane;
        const int i8 = pos / 3, j8 = pos % 3;
        const float4* w84 = (const float4*)dw8_w;
        float4 e0 = {0.f, 0.f, 0.f, 0.f}, e1 = e0, e2 = e0, e3 = e0;
#pragma unroll
        for (int uu = 0; uu < 8; ++uu) {
          const float4 xa = xw4[(8 * i8 + uu) * 7 + 2 * j8];
          const float4 xb = xw4[(8 * i8 + uu) * 7 + 2 * j8 + 1];
          e0 = f4fma4(w84[0 + uu * 2], xa, e0);
          e0 = f4fma4(w84[1 + uu * 2], xb, e0);
          e1 = f4fma4(w84[16 + uu * 2], xa, e1);
          e1 = f4fma4(w84[17 + uu * 2], xb, e1);
          e2 = f4fma4(w84[32 + uu * 2], xa, e2);
          e2 = f4fma4(w84[33 + uu * 2], xb, e2);
          e3 = f4fma4(w84[48 + uu * 2], xa, e3);
          e3 = f4fma4(w84[49 + uu * 2], xb, e3);
        }
        const float d0 = hsum4(e0) + dw8_b[0];
        const float d1 = hsum4(e1) + dw8_b[1];
        const float d2 = hsum4(e2) + dw8_b[2];
        const float d3 = hsum4(e3) + dw8_b[3];
        float z[4];
#pragma unroll
        for (int o = 0; o < 4; ++o) {
          float zz = pw8_b[o];
          zz = fmaf(pw8_w[o * 4 + 0], d0, zz);
          zz = fmaf(pw8_w[o * 4 + 1], d1, zz);
          zz = fmaf(pw8_w[o * 4 + 2], d2, zz);
          zz = fmaf(pw8_w[o * 4 + 3], d3, zz);
          z[o] = fmaxf(zz, 0.f);
        }
#pragma unroll
        for (int k = 0; k < 10; ++k) {
          const float4 h = H84[k * 9 + pos];
          acc[k] += fmaf(h.x, z[0], fmaf(h.y, z[1], fmaf(h.z, z[2], h.w * z[3])));
        }
      }
    }
  }

  // ---- per-wave butterfly reduction ----
#pragma unroll
  for (int k = 0; k < 10; ++k) {
    float v = acc[k];
    v += __shfl_xor(v, 1);
    v += __shfl_xor(v, 2);
    v += __shfl_xor(v, 4);
    v += __shfl_xor(v, 8);
    v += __shfl_xor(v, 16);
    v += __shfl_xor(v, 32);
    acc[k] = v;
  }
  {
    float v = acc[0];
#pragma unroll
    for (int k = 1; k < 10; ++k)
      if (lane == k) v = acc[k];
    if (lane < 10) accw[w][lane] = v;
  }
  __syncthreads();

  // ---- pairwise combine + log-softmax (even waves) ----
  if (pw == 0 && ok) {
    float lg = -1e30f;
    if (lane < 10) lg = accw[w][lane] + accw[w + 1][lane] + C10[lane];
    float mx = lg;
    mx = fmaxf(mx, __shfl_xor(mx, 1));
    mx = fmaxf(mx, __shfl_xor(mx, 2));
    mx = fmaxf(mx, __shfl_xor(mx, 4));
    mx = fmaxf(mx, __shfl_xor(mx, 8));
    float ex = (lane < 10) ? __expf(lg - mx) : 0.f;
    ex += __shfl_xor(ex, 1);
    ex += __shfl_xor(ex, 2);
    ex += __shfl_xor(ex, 4);
    ex += __shfl_xor(ex, 8);
    if (lane < 10) out[img * 10 + lane] = lg - mx - __logf(ex);
  }
}

extern "C" void kernel_launch(void* const* d_in, const int* in_sizes, int n_in,
                              void* d_out, int out_size, void* d_ws, size_t ws_size,
                              hipStream_t stream) {
  const float* x      = (const float*)d_in[0];
  const float* qp     = (const float*)d_in[1];
  const float* dw4_w  = (const float*)d_in[2];
  const float* dw4_b  = (const float*)d_in[3];
  const float* pw4_w  = (const float*)d_in[4];
  const float* pw4_b  = (const float*)d_in[5];
  const float* dw8_w  = (const float*)d_in[6];
  const float* dw8_b  = (const float*)d_in[7];
  const float* pw8_w  = (const float*)d_in[8];
  const float* pw8_b  = (const float*)d_in[9];
  const float* res_w  = (const float*)d_in[10];
  const float* res_b  = (const float*)d_in[11];
  const float* head_w = (const float*)d_in[12];
  const float* head_b = (const float*)d_in[13];
  float* out = (float*)d_out;
  float* ws = (float*)d_ws;
  const int B = in_sizes[0] / 784;

  hipLaunchKernelGGL(prep_kernel, dim3(11), dim3(256), 0, stream,
                     qp, head_w, res_w, res_b, head_b, ws);
  hipLaunchKernelGGL(qmain_kernel, dim3((B + 1) / 2), dim3(256), 0, stream,
                     x, (const float4*)(ws + WS_T),
                     (const float4*)(ws + WS_HQ), ws + WS_WA,
                     (const float4*)(ws + WS_H4), (const float4*)(ws + WS_H8),
                     ws + WS_C10,
                     dw4_w, dw4_b, pw4_w, pw4_b, dw8_w, dw8_b, pw8_w, pw8_b,
                     out, B);
}